// Round 21
// baseline (347.903 us; speedup 1.0000x reference)
//
#include <hip/hip_runtime.h>
#include <math.h>

#define N_NODES 50000
#define N_EDGES 1600000
#define D_IN 128
#define D_HID 128
#define D_OUT 64
#define N_EXPERT 16
#define NB 8     // nodes per block in last kernel
#define GW 16    // nodes per chunk in expert GEMM (1-wave blocks)
#define NPB 4096 // persistent gemm blocks (16 per CU co-resident: LDS/VGPR fit)
#define NBG 16   // nodes per block in gate kernel (50000 % 16 == 0)
#define NGBLK (N_NODES / NBG)   // 3125 gate blocks per layer
#define XR4 33   // padded x-chunk row stride in float4 (132 floats)

// CSR build (bucketed, no global atomics)
#define NBUK 782            // ceil(50000 / 64) coarse buckets (dst >> 6)
#define NFB 250             // phase-1 blocks
#define EPB (N_EDGES / NFB) // 6400 edges per phase-1 block (exact)
#define HM (NBUK * NFB)     // 195500 hist-matrix entries
#define NSB2 ((HM + 255) / 256)  // 764 scan tiles

// bf16 helpers (round-to-nearest-even)
__device__ __forceinline__ unsigned short f2bf(float f) {
    unsigned int u = __float_as_uint(f);
    return (unsigned short)((u + 0x7fffu + ((u >> 16) & 1u)) >> 16);
}
__device__ __forceinline__ float bf2f(unsigned short h) {
    return __uint_as_float((unsigned int)h << 16);
}

// ---------------- gate: logits + softmax-std + argmax ------------------------
// One block = 256 threads = NBG(16) nodes. Thread (e = t&15, j = t>>4).
__global__ __launch_bounds__(256) void gate_kernel(
    const float* __restrict__ x, const float* __restrict__ Wg, const float* __restrict__ bg,
    int* __restrict__ eidx, float* __restrict__ gpart)
{
    __shared__ float xs[NBG][132];           // +4 pad: bank rotation per row
    __shared__ float wgt[N_EXPERT][132];     // transposed gate weights, +4 pad
    __shared__ float sred[NBG];
    const int n0 = blockIdx.x * NBG;
    const int t = threadIdx.x;

    // Wg: 512 float4 coalesced reads -> transposed scalar LDS stores (2/thread)
    {
        const float4* __restrict__ Wg4 = (const float4*)Wg;
        float4 v = Wg4[t];
        int d = t >> 2, e4 = (t & 3) * 4;
        wgt[e4 + 0][d] = v.x; wgt[e4 + 1][d] = v.y; wgt[e4 + 2][d] = v.z; wgt[e4 + 3][d] = v.w;
        v = Wg4[t + 256];
        d += 64;
        wgt[e4 + 0][d] = v.x; wgt[e4 + 1][d] = v.y; wgt[e4 + 2][d] = v.z; wgt[e4 + 3][d] = v.w;
    }
    // x: 16 rows * 32 float4 = 512 float4 (2/thread), coalesced
    {
        int id = t, row = id >> 5, c4 = id & 31;
        *(float4*)&xs[row][4 * c4] = ((const float4*)(x + (size_t)(n0 + row) * 128))[c4];
        id = t + 256; row = id >> 5; c4 = id & 31;
        *(float4*)&xs[row][4 * c4] = ((const float4*)(x + (size_t)(n0 + row) * 128))[c4];
    }
    __syncthreads();

    const int e = t & 15, j = t >> 4;
    float lg = bg[e];
    #pragma unroll
    for (int d4 = 0; d4 < 32; ++d4) {        // d-ascending FMA order preserved
        const float4 xv = *(const float4*)&xs[j][4 * d4];
        const float4 wv = *(const float4*)&wgt[e][4 * d4];
        lg = fmaf(xv.x, wv.x, lg);
        lg = fmaf(xv.y, wv.y, lg);
        lg = fmaf(xv.z, wv.z, lg);
        lg = fmaf(xv.w, wv.w, lg);
    }

    // 16-lane-group reductions (lanes of one node are contiguous)
    float mx = lg;
    #pragma unroll
    for (int m = 8; m >= 1; m >>= 1) mx = fmaxf(mx, __shfl_xor(mx, m, 16));
    const float ex = expf(lg - mx);
    float se = ex;
    #pragma unroll
    for (int m = 8; m >= 1; m >>= 1) se += __shfl_xor(se, m, 16);
    const float p = ex / se;
    const float dm = p - (1.f / 16.f);
    float var = dm * dm;
    #pragma unroll
    for (int m = 8; m >= 1; m >>= 1) var += __shfl_xor(var, m, 16);

    // argmax over logits (== argmax over softmax), first-index on ties
    float bv = lg; int bi = e;
    #pragma unroll
    for (int m = 8; m >= 1; m >>= 1) {
        const float ov = __shfl_xor(bv, m, 16);
        const int oi = __shfl_xor(bi, m, 16);
        if (ov > bv || (ov == bv && oi < bi)) { bv = ov; bi = oi; }
    }
    if (e == 0) {
        eidx[n0 + j] = bi;
        sred[j] = sqrtf(var * (1.f / 15.f));
    }
    __syncthreads();
    if (t == 0) {
        float s = 0.f;
        #pragma unroll
        for (int jj = 0; jj < NBG; ++jj) s += sred[jj];
        gpart[blockIdx.x] = s;
    }
}

// ---------------- expert bucketing: hist16 -> scan16 -> scatter16 ------------
__global__ __launch_bounds__(256) void hist16_kernel(
    const int* __restrict__ eidx, int* __restrict__ ecnt)
{
    __shared__ int lcnt[N_EXPERT];
    const int t = threadIdx.x;
    const int n = blockIdx.x * 256 + t;
    if (t < N_EXPERT) lcnt[t] = 0;
    __syncthreads();
    if (n < N_NODES) atomicAdd(&lcnt[eidx[n]], 1);
    __syncthreads();
    if (t < N_EXPERT && lcnt[t] > 0) atomicAdd(&ecnt[t], lcnt[t]);
}

// also emits per-expert CHUNK offsets (coff, GW-node chunks).
__global__ void scan16_kernel(const int* __restrict__ ecnt,
                              int* __restrict__ eoff, int* __restrict__ ecur,
                              int* __restrict__ coff)
{
    if (threadIdx.x == 0) {
        int s = 0, c = 0;
        #pragma unroll
        for (int e = 0; e < N_EXPERT; ++e) {
            eoff[e] = s; ecur[e] = s; coff[e] = c;
            s += ecnt[e];
            c += (ecnt[e] + GW - 1) / GW;
        }
        eoff[N_EXPERT] = s;
        coff[N_EXPERT] = c;
    }
}

__global__ __launch_bounds__(256) void scatter16_kernel(
    const int* __restrict__ eidx, int* __restrict__ ecur, int* __restrict__ elist)
{
    __shared__ int lcnt[N_EXPERT];
    __shared__ int lbase[N_EXPERT];
    const int t = threadIdx.x;
    const int n = blockIdx.x * 256 + t;
    if (t < N_EXPERT) lcnt[t] = 0;
    __syncthreads();
    int e = 0, lpos = 0;
    if (n < N_NODES) { e = eidx[n]; lpos = atomicAdd(&lcnt[e], 1); }
    __syncthreads();
    if (t < N_EXPERT && lcnt[t] > 0) lbase[t] = atomicAdd(&ecur[t], lcnt[t]);
    __syncthreads();
    if (n < N_NODES) elist[lbase[e] + lpos] = n;
}

// ---------------- per-expert GEMM: y[n] = x[n] @ We[e] + be[e] ---------------
// Persistent grid-stride blocks, eoff/coff cached in LDS (R19: occupancy
// 5.5->18%, 107->~50 us). NPB 2048->4096: 16 blocks/CU still fit (LDS 135 KB,
// VGPR 82K) -> doubles co-resident waves again. Chunk body, FMA order,
// stores: identical to R14 (bit-identical output).
__global__ __launch_bounds__(64) void expert_gemm_kernel(
    const float* __restrict__ x, const float* __restrict__ We, const float* __restrict__ be,
    const int* __restrict__ eoff, const int* __restrict__ coff,
    const int* __restrict__ elist, unsigned short* __restrict__ y)
{
    __shared__ float xsd[GW * 132];  // 8448 B, padded rows (33 float4)
    __shared__ int s_eoff[N_EXPERT + 1];
    __shared__ int s_coff[N_EXPERT + 1];
    const int t = threadIdx.x;
    if (t <= N_EXPERT) { s_eoff[t] = eoff[t]; s_coff[t] = coff[t]; }
    __syncthreads();
    const int total = s_coff[N_EXPERT];

    for (int i = blockIdx.x; i < total; i += NPB) {
        // map chunk -> expert (16-entry LDS walk, block-uniform)
        int e = 0;
        while (s_coff[e + 1] <= i) ++e;
        const int row0 = s_eoff[e];
        const int row1 = s_eoff[e + 1];
        const int start = row0 + (i - s_coff[e]) * GW;

        const float2* __restrict__ Wv2 = (const float2*)(We + (size_t)e * 16384);
        const float4* __restrict__ Xv = (const float4*)xsd;
        const float2 bv = ((const float2*)be)[e * 64 + t];

        // stage 16 node rows (512 float4 over 64 threads = 8 iters, coalesced)
        #pragma unroll
        for (int s = 0; s < 8; ++s) {
            const int id = t + 64 * s;
            const int r = id >> 5;
            const int c4 = id & 31;
            const int idx = start + r;
            const int node = elist[idx < row1 ? idx : start];
            ((float4*)xsd)[r * XR4 + c4] = ((const float4*)(x + (size_t)node * 128))[c4];
        }
        __syncthreads();

        float2 acc[GW];
        #pragma unroll
        for (int k = 0; k < GW; ++k) acc[k] = bv;   // bias-init (baseline order)

        #pragma unroll 2
        for (int d4 = 0; d4 < 32; ++d4) {
            float2 w0 = Wv2[(4 * d4 + 0) * 64 + t];
            float2 w1 = Wv2[(4 * d4 + 1) * 64 + t];
            float2 w2 = Wv2[(4 * d4 + 2) * 64 + t];
            float2 w3 = Wv2[(4 * d4 + 3) * 64 + t];
            #pragma unroll
            for (int k = 0; k < GW; ++k) {
                const float4 xv = Xv[k * XR4 + d4];   // wave-broadcast
                acc[k].x = fmaf(xv.x, w0.x, acc[k].x);
                acc[k].y = fmaf(xv.x, w0.y, acc[k].y);
                acc[k].x = fmaf(xv.y, w1.x, acc[k].x);
                acc[k].y = fmaf(xv.y, w1.y, acc[k].y);
                acc[k].x = fmaf(xv.z, w2.x, acc[k].x);
                acc[k].y = fmaf(xv.z, w2.y, acc[k].y);
                acc[k].x = fmaf(xv.w, w3.x, acc[k].x);
                acc[k].y = fmaf(xv.w, w3.y, acc[k].y);
            }
        }

        #pragma unroll
        for (int k = 0; k < GW; ++k) {
            const int idx = start + k;
            if (idx < row1) {
                ushort2 o;
                o.x = f2bf(acc[k].x);
                o.y = f2bf(acc[k].y);
                *(ushort2*)&y[(size_t)elist[idx] * 128 + 2 * t] = o;
            }
        }

        __syncthreads();   // xsd reads done before next-iteration restage
    }
}

// ---------------- final plain linear 128 -> 64, 8 nodes/block (bf16 out) -----
__global__ __launch_bounds__(64) void last_kernel(
    const float* __restrict__ h, const float* __restrict__ W,
    unsigned short* __restrict__ y)
{
    __shared__ float xs[NB][128];
    const int n0 = blockIdx.x * NB, t = threadIdx.x;
    #pragma unroll
    for (int j = 0; j < NB; ++j) {
        xs[j][t] = h[(size_t)(n0 + j) * 128 + t];
        xs[j][t + 64] = h[(size_t)(n0 + j) * 128 + t + 64];
    }
    __syncthreads();
    float a0 = 0.f, a1 = 0.f, a2 = 0.f, a3 = 0.f;
    float a4 = 0.f, a5 = 0.f, a6 = 0.f, a7 = 0.f;
    #pragma unroll 4
    for (int d = 0; d < 128; ++d) {
        const float w = W[d * 64 + t];
        a0 = fmaf(xs[0][d], w, a0);
        a1 = fmaf(xs[1][d], w, a1);
        a2 = fmaf(xs[2][d], w, a2);
        a3 = fmaf(xs[3][d], w, a3);
        a4 = fmaf(xs[4][d], w, a4);
        a5 = fmaf(xs[5][d], w, a5);
        a6 = fmaf(xs[6][d], w, a6);
        a7 = fmaf(xs[7][d], w, a7);
    }
    y[(size_t)(n0 + 0) * 64 + t] = f2bf(a0);
    y[(size_t)(n0 + 1) * 64 + t] = f2bf(a1);
    y[(size_t)(n0 + 2) * 64 + t] = f2bf(a2);
    y[(size_t)(n0 + 3) * 64 + t] = f2bf(a3);
    y[(size_t)(n0 + 4) * 64 + t] = f2bf(a4);
    y[(size_t)(n0 + 5) * 64 + t] = f2bf(a5);
    y[(size_t)(n0 + 6) * 64 + t] = f2bf(a6);
    y[(size_t)(n0 + 7) * 64 + t] = f2bf(a7);
}

// ============== CSR build: bucketed counting sort, NO global atomics =========
__global__ __launch_bounds__(256) void bhist_kernel(
    const int* __restrict__ edst, int* __restrict__ hist_g)
{
    __shared__ int lcnt[NBUK];
    const int t = threadIdx.x;
    const int b = blockIdx.x;
    for (int i = t; i < NBUK; i += 256) lcnt[i] = 0;
    __syncthreads();
    const int e0 = b * EPB;
    #pragma unroll 5
    for (int k = 0; k < EPB / 256; ++k)
        atomicAdd(&lcnt[edst[e0 + k * 256 + t] >> 6], 1);
    __syncthreads();
    for (int i = t; i < NBUK; i += 256) hist_g[i * NFB + b] = lcnt[i];
}

__global__ __launch_bounds__(256) void hpre_kernel(
    const int* __restrict__ hist_g, int* __restrict__ tsum)
{
    __shared__ int ws[4];
    const int t = threadIdx.x;
    const int idx = blockIdx.x * 256 + t;
    int v = (idx < HM) ? hist_g[idx] : 0;
    #pragma unroll
    for (int m = 32; m >= 1; m >>= 1) v += __shfl_xor(v, m, 64);
    if ((t & 63) == 0) ws[t >> 6] = v;
    __syncthreads();
    if (t == 0) tsum[blockIdx.x] = ws[0] + ws[1] + ws[2] + ws[3];
}

__global__ __launch_bounds__(1024) void hscan_kernel(
    const int* __restrict__ tsum, int* __restrict__ tbase, int* __restrict__ rowptr_last)
{
    __shared__ int buf[1024];
    const int t = threadIdx.x;
    const int v = (t < NSB2) ? tsum[t] : 0;
    buf[t] = v;
    __syncthreads();
    for (int off = 1; off < 1024; off <<= 1) {
        const int add = (t >= off) ? buf[t - off] : 0;
        __syncthreads();
        buf[t] += add;
        __syncthreads();
    }
    if (t < NSB2) tbase[t] = buf[t] - v;
    if (t == 0) rowptr_last[0] = N_EDGES;
}

__global__ __launch_bounds__(256) void hwb_kernel(
    const int* __restrict__ hist_g, const int* __restrict__ tbase,
    int* __restrict__ base_g)
{
    __shared__ int buf[256];
    const int t = threadIdx.x;
    const int idx = blockIdx.x * 256 + t;
    const int v = (idx < HM) ? hist_g[idx] : 0;
    buf[t] = v;
    __syncthreads();
    for (int off = 1; off < 256; off <<= 1) {
        const int add = (t >= off) ? buf[t - off] : 0;
        __syncthreads();
        buf[t] += add;
        __syncthreads();
    }
    if (idx < HM) base_g[idx] = buf[t] - v + tbase[blockIdx.x];
}

__global__ __launch_bounds__(256) void bscatter_kernel(
    const int* __restrict__ esrc, const int* __restrict__ edst,
    const int* __restrict__ base_g, unsigned int* __restrict__ packed)
{
    __shared__ int rcur[NBUK];
    const int t = threadIdx.x;
    const int b = blockIdx.x;
    for (int i = t; i < NBUK; i += 256) rcur[i] = base_g[i * NFB + b];
    __syncthreads();
    const int e0 = b * EPB;
    #pragma unroll 5
    for (int k = 0; k < EPB / 256; ++k) {
        const int i = e0 + k * 256 + t;
        const int src = esrc[i];
        const int dst = edst[i];
        const int p = atomicAdd(&rcur[dst >> 6], 1);
        packed[p] = ((unsigned int)dst << 16) | (unsigned int)src;
    }
}

__global__ __launch_bounds__(256) void bfine_kernel(
    const unsigned int* __restrict__ packed, const int* __restrict__ base_g,
    int* __restrict__ rowptr, unsigned short* __restrict__ csr_src)
{
    __shared__ int cnt64[64], cur64[64], sexcl[64];
    const int t = threadIdx.x;
    const int j = blockIdx.x;
    const int s0 = base_g[j * NFB];
    const int s1 = (j + 1 < NBUK) ? base_g[(j + 1) * NFB] : N_EDGES;
    if (t < 64) cnt64[t] = 0;
    __syncthreads();
    for (int i = s0 + t; i < s1; i += 256)
        atomicAdd(&cnt64[(packed[i] >> 16) & 63], 1);
    __syncthreads();
    if (t == 0) {
        int run = 0;
        #pragma unroll
        for (int l = 0; l < 64; ++l) { sexcl[l] = run; run += cnt64[l]; }
    }
    __syncthreads();
    if (t < 64) {
        cur64[t] = 0;
        const int n = (j << 6) + t;
        if (n < N_NODES) rowptr[n] = s0 + sexcl[t];
    }
    __syncthreads();
    for (int i = s0 + t; i < s1; i += 256) {
        const unsigned int pk = packed[i];
        const int dl = (pk >> 16) & 63;
        const int p = atomicAdd(&cur64[dl], 1);
        csr_src[s0 + sexcl[dl] + p] = (unsigned short)(pk & 0xffff);
    }
}

// ---------------- gather aggregation: out[n] = bias + sum_{e in row n} h[src] -
// h rows are BF16. 32/16/8/4/1 chain tiers: up to 8 KB random-row bytes in
// flight per block (bytes-in-flight bound; R20 measured 6.3 TB/s effective).
template <int D, bool RELU>
__global__ __launch_bounds__(D) void gather_kernel(
    const unsigned short* __restrict__ h, const int* __restrict__ rowptr,
    const unsigned short* __restrict__ csr_src, const float* __restrict__ bias,
    float* __restrict__ out)
{
    const int n = blockIdx.x, t = threadIdx.x;
    const int s0 = rowptr[n], s1 = rowptr[n + 1];
    float a0 = bias[t], a1 = 0.f, a2 = 0.f, a3 = 0.f;
    float a4 = 0.f, a5 = 0.f, a6 = 0.f, a7 = 0.f;
    float a8 = 0.f, a9 = 0.f, aA = 0.f, aB = 0.f;
    float aC = 0.f, aD = 0.f, aE = 0.f, aF = 0.f;
    int e = s0;
    for (; e + 31 < s1; e += 32) {
        #pragma unroll
        for (int q = 0; q < 2; ++q) {
            const int b = e + q * 16;
            const int i0 = csr_src[b + 0];
            const int i1 = csr_src[b + 1];
            const int i2 = csr_src[b + 2];
            const int i3 = csr_src[b + 3];
            const int i4 = csr_src[b + 4];
            const int i5 = csr_src[b + 5];
            const int i6 = csr_src[b + 6];
            const int i7 = csr_src[b + 7];
            const int i8 = csr_src[b + 8];
            const int i9 = csr_src[b + 9];
            const int iA = csr_src[b + 10];
            const int iB = csr_src[b + 11];
            const int iC = csr_src[b + 12];
            const int iD = csr_src[b + 13];
            const int iE = csr_src[b + 14];
            const int iF = csr_src[b + 15];
            a0 += bf2f(h[(size_t)i0 * D + t]);
            a1 += bf2f(h[(size_t)i1 * D + t]);
            a2 += bf2f(h[(size_t)i2 * D + t]);
            a3 += bf2f(h[(size_t)i3 * D + t]);
            a4 += bf2f(h[(size_t)i4 * D + t]);
            a5 += bf2f(h[(size_t)i5 * D + t]);
            a6 += bf2f(h[(size_t)i6 * D + t]);
            a7 += bf2f(h[(size_t)i7 * D + t]);
            a8 += bf2f(h[(size_t)i8 * D + t]);
            a9 += bf2f(h[(size_t)i9 * D + t]);
            aA += bf2f(h[(size_t)iA * D + t]);
            aB += bf2f(h[(size_t)iB * D + t]);
            aC += bf2f(h[(size_t)iC * D + t]);
            aD += bf2f(h[(size_t)iD * D + t]);
            aE += bf2f(h[(size_t)iE * D + t]);
            aF += bf2f(h[(size_t)iF * D + t]);
        }
    }
    for (; e + 15 < s1; e += 16) {
        const int i0 = csr_src[e + 0];
        const int i1 = csr_src[e + 1];
        const int i2 = csr_src[e + 2];
        const int i3 = csr_src[e + 3];
        const int i4 = csr_src[e + 4];
        const int i5 = csr_src[e + 5];
        const int i6 = csr_src[e + 6];
        const int i7 = csr_src[e + 7];
        const int i8 = csr_src[e + 8];
        const int i9 = csr_src[e + 9];
        const int iA = csr_src[e + 10];
        const int iB = csr_src[e + 11];
        const int iC = csr_src[e + 12];
        const int iD = csr_src[e + 13];
        const int iE = csr_src[e + 14];
        const int iF = csr_src[e + 15];
        a0 += bf2f(h[(size_t)i0 * D + t]);
        a1 += bf2f(h[(size_t)i1 * D + t]);
        a2 += bf2f(h[(size_t)i2 * D + t]);
        a3 += bf2f(h[(size_t)i3 * D + t]);
        a4 += bf2f(h[(size_t)i4 * D + t]);
        a5 += bf2f(h[(size_t)i5 * D + t]);
        a6 += bf2f(h[(size_t)i6 * D + t]);
        a7 += bf2f(h[(size_t)i7 * D + t]);
        a8 += bf2f(h[(size_t)i8 * D + t]);
        a9 += bf2f(h[(size_t)i9 * D + t]);
        aA += bf2f(h[(size_t)iA * D + t]);
        aB += bf2f(h[(size_t)iB * D + t]);
        aC += bf2f(h[(size_t)iC * D + t]);
        aD += bf2f(h[(size_t)iD * D + t]);
        aE += bf2f(h[(size_t)iE * D + t]);
        aF += bf2f(h[(size_t)iF * D + t]);
    }
    for (; e + 7 < s1; e += 8) {
        const int i0 = csr_src[e + 0];
        const int i1 = csr_src[e + 1];
        const int i2 = csr_src[e + 2];
        const int i3 = csr_src[e + 3];
        const int i4 = csr_src[e + 4];
        const int i5 = csr_src[e + 5];
        const int i6 = csr_src[e + 6];
        const int i7 = csr_src[e + 7];
        a0 += bf2f(h[(size_t)i0 * D + t]);
        a1 += bf2f(h[(size_t)i1 * D + t]);
        a2 += bf2f(h[(size_t)i2 * D + t]);
        a3 += bf2f(h[(size_t)i3 * D + t]);
        a4 += bf2f(h[(size_t)i4 * D + t]);
        a5 += bf2f(h[(size_t)i5 * D + t]);
        a6 += bf2f(h[(size_t)i6 * D + t]);
        a7 += bf2f(h[(size_t)i7 * D + t]);
    }
    for (; e + 3 < s1; e += 4) {
        const int i0 = csr_src[e + 0];
        const int i1 = csr_src[e + 1];
        const int i2 = csr_src[e + 2];
        const int i3 = csr_src[e + 3];
        a0 += bf2f(h[(size_t)i0 * D + t]);
        a1 += bf2f(h[(size_t)i1 * D + t]);
        a2 += bf2f(h[(size_t)i2 * D + t]);
        a3 += bf2f(h[(size_t)i3 * D + t]);
    }
    for (; e < s1; ++e) a0 += bf2f(h[(size_t)csr_src[e] * D + t]);
    float acc = (((a0 + a1) + (a2 + a3)) + ((a4 + a5) + (a6 + a7)))
              + (((a8 + a9) + (aA + aB)) + ((aC + aD) + (aE + aF)));
    if (RELU) acc = fmaxf(acc, 0.f);
    out[(size_t)n * D + t] = acc;
}

// ---------------- finalize: reduce 2*NGBLK gate partials + write tail --------
__global__ __launch_bounds__(1024) void finalize_kernel(
    const float* __restrict__ gpart, float* __restrict__ out_tail)
{
    __shared__ float wsum[16];
    const int t = threadIdx.x;
    float s = 0.f;
    for (int i = t; i < 2 * NGBLK; i += 1024) s += gpart[i];
    #pragma unroll
    for (int m = 32; m >= 1; m >>= 1) s += __shfl_xor(s, m, 64);
    if ((t & 63) == 0) wsum[t >> 6] = s;
    __syncthreads();
    if (t == 0) {
        float tot = 0.f;
        #pragma unroll
        for (int w = 0; w < 16; ++w) tot += wsum[w];
        out_tail[0] = tot * (0.5f / (float)N_NODES);
        out_tail[1] = 1.0f;
    }
}

extern "C" void kernel_launch(void* const* d_in, const int* in_sizes, int n_in,
                              void* d_out, int out_size, void* d_ws, size_t ws_size,
                              hipStream_t stream)
{
    const float* x     = (const float*)d_in[0];
    const int*   edge  = (const int*)d_in[1];
    const float* Wg1   = (const float*)d_in[2];
    const float* bg1   = (const float*)d_in[3];
    const float* We1   = (const float*)d_in[4];
    const float* be1   = (const float*)d_in[5];
    const float* b1    = (const float*)d_in[6];
    const float* Wg2   = (const float*)d_in[7];
    const float* bg2   = (const float*)d_in[8];
    const float* We2   = (const float*)d_in[9];
    const float* be2   = (const float*)d_in[10];
    const float* b2    = (const float*)d_in[11];
    const float* Wlast = (const float*)d_in[12];
    const float* blast = (const float*)d_in[13];
    float* out = (float*)d_out;

    const int* esrc = edge;
    const int* edst = edge + N_EDGES;

    char* ws = (char*)d_ws;
    size_t off = 0;
    float* gpart = (float*)(ws + off); off += (size_t)2 * NGBLK * 4 + 252; off &= ~(size_t)255;
    float* A = (float*)(ws + off); off += (size_t)N_NODES * 128 * 4;
    float* B = (float*)(ws + off); off += (size_t)N_NODES * 128 * 4;
    int* rowptr = (int*)(ws + off); off += (size_t)(N_NODES + 1) * 4 + 252; off &= ~(size_t)255;
    int* eidx = (int*)(ws + off); off += (size_t)N_NODES * 4 + 252; off &= ~(size_t)255;
    unsigned short* csr_src = (unsigned short*)(ws + off); off += (size_t)N_EDGES * 2 + 252; off &= ~(size_t)255;
    int* elist = (int*)(ws + off); off += (size_t)N_NODES * 4 + 252; off &= ~(size_t)255;
    int* meta = (int*)(ws + off); off += 512;
    int* ecnt = meta;          // 16
    int* eoff = meta + 16;     // 17
    int* ecur = meta + 33;     // 16
    int* coff = meta + 49;     // 17 chunk offsets

    // bf16 intermediate h (per-expert / last outputs), lives in A's slab
    unsigned short* Abf = (unsigned short*)A;     // 12.8 MB (128-dim) / 6.4 MB (64-dim)

    // CSR temporaries alias A and B (both dead until layer 1 compute):
    unsigned int* packed = (unsigned int*)A;      // 6.4 MB <= 25.6 MB
    int* hist_g = (int*)B;                        // HM ints
    int* base_g = hist_g + HM;                    // HM ints
    int* tsum   = base_g + HM;                    // NSB2 ints
    int* tbase  = tsum + NSB2;                    // NSB2 ints (total ~1.6 MB)

    // ---- CSR build (no global atomics) ----
    bhist_kernel<<<NFB, 256, 0, stream>>>(edst, hist_g);
    hpre_kernel<<<NSB2, 256, 0, stream>>>(hist_g, tsum);
    hscan_kernel<<<1, 1024, 0, stream>>>(tsum, tbase, rowptr + N_NODES);
    hwb_kernel<<<NSB2, 256, 0, stream>>>(hist_g, tbase, base_g);
    bscatter_kernel<<<NFB, 256, 0, stream>>>(esrc, edst, base_g, packed);
    bfine_kernel<<<NBUK, 256, 0, stream>>>(packed, base_g, rowptr, csr_src);

    const int nbk = (N_NODES + 255) / 256;

    // ---- layer 1 ----
    gate_kernel<<<NGBLK, 256, 0, stream>>>(x, Wg1, bg1, eidx, gpart);
    hipMemsetAsync(ecnt, 0, 64, stream);
    hist16_kernel<<<nbk, 256, 0, stream>>>(eidx, ecnt);
    scan16_kernel<<<1, 64, 0, stream>>>(ecnt, eoff, ecur, coff);
    scatter16_kernel<<<nbk, 256, 0, stream>>>(eidx, ecur, elist);
    expert_gemm_kernel<<<NPB, 64, 0, stream>>>(x, We1, be1, eoff, coff, elist, Abf);
    gather_kernel<128, true><<<N_NODES, 128, 0, stream>>>(Abf, rowptr, csr_src, b1, B);

    // ---- layer 2 ----
    gate_kernel<<<NGBLK, 256, 0, stream>>>(B, Wg2, bg2, eidx, gpart + NGBLK);
    hipMemsetAsync(ecnt, 0, 64, stream);
    hist16_kernel<<<nbk, 256, 0, stream>>>(eidx, ecnt);
    scan16_kernel<<<1, 64, 0, stream>>>(ecnt, eoff, ecur, coff);
    scatter16_kernel<<<nbk, 256, 0, stream>>>(eidx, ecur, elist);
    expert_gemm_kernel<<<NPB, 64, 0, stream>>>(B, We2, be2, eoff, coff, elist, Abf);
    gather_kernel<128, true><<<N_NODES, 128, 0, stream>>>(Abf, rowptr, csr_src, b2, B);

    // ---- layer 3 (plain GCNConv) ----
    last_kernel<<<N_NODES / NB, 64, 0, stream>>>(B, Wlast, Abf);
    gather_kernel<64, false><<<N_NODES, 64, 0, stream>>>(Abf, rowptr, csr_src, blast, out);

    finalize_kernel<<<1, 1024, 0, stream>>>(gpart, out + (size_t)N_NODES * 64);
}

// Round 22
// 339.708 us; speedup vs baseline: 1.0241x; 1.0241x over previous
//
#include <hip/hip_runtime.h>
#include <math.h>

#define N_NODES 50000
#define N_EDGES 1600000
#define D_IN 128
#define D_HID 128
#define D_OUT 64
#define N_EXPERT 16
#define NB 8     // nodes per block in last kernel
#define GW 16    // nodes per chunk in expert GEMM (1-wave blocks)
#define NPB 4096 // persistent gemm blocks (16 per CU co-resident; R21: ~-4us vs 2048)
#define NBG 16   // nodes per block in gate kernel (50000 % 16 == 0)
#define NGBLK (N_NODES / NBG)   // 3125 gate blocks per layer
#define XR4 33   // padded x-chunk row stride in float4 (132 floats)

// CSR build (bucketed, no global atomics)
#define NBUK 782            // ceil(50000 / 64) coarse buckets (dst >> 6)
#define NFB 250             // phase-1 blocks
#define EPB (N_EDGES / NFB) // 6400 edges per phase-1 block (exact)
#define HM (NBUK * NFB)     // 195500 hist-matrix entries
#define NSB2 ((HM + 255) / 256)  // 764 scan tiles

// bf16 helpers (round-to-nearest-even)
__device__ __forceinline__ unsigned short f2bf(float f) {
    unsigned int u = __float_as_uint(f);
    return (unsigned short)((u + 0x7fffu + ((u >> 16) & 1u)) >> 16);
}
__device__ __forceinline__ float bf2f(unsigned short h) {
    return __uint_as_float((unsigned int)h << 16);
}

// ---------------- gate: logits + softmax-std + argmax ------------------------
// One block = 256 threads = NBG(16) nodes. Thread (e = t&15, j = t>>4).
__global__ __launch_bounds__(256) void gate_kernel(
    const float* __restrict__ x, const float* __restrict__ Wg, const float* __restrict__ bg,
    int* __restrict__ eidx, float* __restrict__ gpart)
{
    __shared__ float xs[NBG][132];           // +4 pad: bank rotation per row
    __shared__ float wgt[N_EXPERT][132];     // transposed gate weights, +4 pad
    __shared__ float sred[NBG];
    const int n0 = blockIdx.x * NBG;
    const int t = threadIdx.x;

    // Wg: 512 float4 coalesced reads -> transposed scalar LDS stores (2/thread)
    {
        const float4* __restrict__ Wg4 = (const float4*)Wg;
        float4 v = Wg4[t];
        int d = t >> 2, e4 = (t & 3) * 4;
        wgt[e4 + 0][d] = v.x; wgt[e4 + 1][d] = v.y; wgt[e4 + 2][d] = v.z; wgt[e4 + 3][d] = v.w;
        v = Wg4[t + 256];
        d += 64;
        wgt[e4 + 0][d] = v.x; wgt[e4 + 1][d] = v.y; wgt[e4 + 2][d] = v.z; wgt[e4 + 3][d] = v.w;
    }
    // x: 16 rows * 32 float4 = 512 float4 (2/thread), coalesced
    {
        int id = t, row = id >> 5, c4 = id & 31;
        *(float4*)&xs[row][4 * c4] = ((const float4*)(x + (size_t)(n0 + row) * 128))[c4];
        id = t + 256; row = id >> 5; c4 = id & 31;
        *(float4*)&xs[row][4 * c4] = ((const float4*)(x + (size_t)(n0 + row) * 128))[c4];
    }
    __syncthreads();

    const int e = t & 15, j = t >> 4;
    float lg = bg[e];
    #pragma unroll
    for (int d4 = 0; d4 < 32; ++d4) {        // d-ascending FMA order preserved
        const float4 xv = *(const float4*)&xs[j][4 * d4];
        const float4 wv = *(const float4*)&wgt[e][4 * d4];
        lg = fmaf(xv.x, wv.x, lg);
        lg = fmaf(xv.y, wv.y, lg);
        lg = fmaf(xv.z, wv.z, lg);
        lg = fmaf(xv.w, wv.w, lg);
    }

    // 16-lane-group reductions (lanes of one node are contiguous)
    float mx = lg;
    #pragma unroll
    for (int m = 8; m >= 1; m >>= 1) mx = fmaxf(mx, __shfl_xor(mx, m, 16));
    const float ex = expf(lg - mx);
    float se = ex;
    #pragma unroll
    for (int m = 8; m >= 1; m >>= 1) se += __shfl_xor(se, m, 16);
    const float p = ex / se;
    const float dm = p - (1.f / 16.f);
    float var = dm * dm;
    #pragma unroll
    for (int m = 8; m >= 1; m >>= 1) var += __shfl_xor(var, m, 16);

    // argmax over logits (== argmax over softmax), first-index on ties
    float bv = lg; int bi = e;
    #pragma unroll
    for (int m = 8; m >= 1; m >>= 1) {
        const float ov = __shfl_xor(bv, m, 16);
        const int oi = __shfl_xor(bi, m, 16);
        if (ov > bv || (ov == bv && oi < bi)) { bv = ov; bi = oi; }
    }
    if (e == 0) {
        eidx[n0 + j] = bi;
        sred[j] = sqrtf(var * (1.f / 15.f));
    }
    __syncthreads();
    if (t == 0) {
        float s = 0.f;
        #pragma unroll
        for (int jj = 0; jj < NBG; ++jj) s += sred[jj];
        gpart[blockIdx.x] = s;
    }
}

// ---------------- expert bucketing: hist16 -> scan16 -> scatter16 ------------
__global__ __launch_bounds__(256) void hist16_kernel(
    const int* __restrict__ eidx, int* __restrict__ ecnt)
{
    __shared__ int lcnt[N_EXPERT];
    const int t = threadIdx.x;
    const int n = blockIdx.x * 256 + t;
    if (t < N_EXPERT) lcnt[t] = 0;
    __syncthreads();
    if (n < N_NODES) atomicAdd(&lcnt[eidx[n]], 1);
    __syncthreads();
    if (t < N_EXPERT && lcnt[t] > 0) atomicAdd(&ecnt[t], lcnt[t]);
}

// also emits per-expert CHUNK offsets (coff, GW-node chunks).
__global__ void scan16_kernel(const int* __restrict__ ecnt,
                              int* __restrict__ eoff, int* __restrict__ ecur,
                              int* __restrict__ coff)
{
    if (threadIdx.x == 0) {
        int s = 0, c = 0;
        #pragma unroll
        for (int e = 0; e < N_EXPERT; ++e) {
            eoff[e] = s; ecur[e] = s; coff[e] = c;
            s += ecnt[e];
            c += (ecnt[e] + GW - 1) / GW;
        }
        eoff[N_EXPERT] = s;
        coff[N_EXPERT] = c;
    }
}

__global__ __launch_bounds__(256) void scatter16_kernel(
    const int* __restrict__ eidx, int* __restrict__ ecur, int* __restrict__ elist)
{
    __shared__ int lcnt[N_EXPERT];
    __shared__ int lbase[N_EXPERT];
    const int t = threadIdx.x;
    const int n = blockIdx.x * 256 + t;
    if (t < N_EXPERT) lcnt[t] = 0;
    __syncthreads();
    int e = 0, lpos = 0;
    if (n < N_NODES) { e = eidx[n]; lpos = atomicAdd(&lcnt[e], 1); }
    __syncthreads();
    if (t < N_EXPERT && lcnt[t] > 0) lbase[t] = atomicAdd(&ecur[t], lcnt[t]);
    __syncthreads();
    if (n < N_NODES) elist[lbase[e] + lpos] = n;
}

// ---------------- per-expert GEMM: y[n] = x[n] @ We[e] + be[e] ---------------
// Persistent grid-stride blocks (NPB=4096, 16/CU), eoff/coff cached in LDS.
// Chunk body, FMA order, stores: identical to R14 (bit-identical output).
__global__ __launch_bounds__(64) void expert_gemm_kernel(
    const float* __restrict__ x, const float* __restrict__ We, const float* __restrict__ be,
    const int* __restrict__ eoff, const int* __restrict__ coff,
    const int* __restrict__ elist, unsigned short* __restrict__ y)
{
    __shared__ float xsd[GW * 132];  // 8448 B, padded rows (33 float4)
    __shared__ int s_eoff[N_EXPERT + 1];
    __shared__ int s_coff[N_EXPERT + 1];
    const int t = threadIdx.x;
    if (t <= N_EXPERT) { s_eoff[t] = eoff[t]; s_coff[t] = coff[t]; }
    __syncthreads();
    const int total = s_coff[N_EXPERT];

    for (int i = blockIdx.x; i < total; i += NPB) {
        // map chunk -> expert (16-entry LDS walk, block-uniform)
        int e = 0;
        while (s_coff[e + 1] <= i) ++e;
        const int row0 = s_eoff[e];
        const int row1 = s_eoff[e + 1];
        const int start = row0 + (i - s_coff[e]) * GW;

        const float2* __restrict__ Wv2 = (const float2*)(We + (size_t)e * 16384);
        const float4* __restrict__ Xv = (const float4*)xsd;
        const float2 bv = ((const float2*)be)[e * 64 + t];

        // stage 16 node rows (512 float4 over 64 threads = 8 iters, coalesced)
        #pragma unroll
        for (int s = 0; s < 8; ++s) {
            const int id = t + 64 * s;
            const int r = id >> 5;
            const int c4 = id & 31;
            const int idx = start + r;
            const int node = elist[idx < row1 ? idx : start];
            ((float4*)xsd)[r * XR4 + c4] = ((const float4*)(x + (size_t)node * 128))[c4];
        }
        __syncthreads();

        float2 acc[GW];
        #pragma unroll
        for (int k = 0; k < GW; ++k) acc[k] = bv;   // bias-init (baseline order)

        #pragma unroll 2
        for (int d4 = 0; d4 < 32; ++d4) {
            float2 w0 = Wv2[(4 * d4 + 0) * 64 + t];
            float2 w1 = Wv2[(4 * d4 + 1) * 64 + t];
            float2 w2 = Wv2[(4 * d4 + 2) * 64 + t];
            float2 w3 = Wv2[(4 * d4 + 3) * 64 + t];
            #pragma unroll
            for (int k = 0; k < GW; ++k) {
                const float4 xv = Xv[k * XR4 + d4];   // wave-broadcast
                acc[k].x = fmaf(xv.x, w0.x, acc[k].x);
                acc[k].y = fmaf(xv.x, w0.y, acc[k].y);
                acc[k].x = fmaf(xv.y, w1.x, acc[k].x);
                acc[k].y = fmaf(xv.y, w1.y, acc[k].y);
                acc[k].x = fmaf(xv.z, w2.x, acc[k].x);
                acc[k].y = fmaf(xv.z, w2.y, acc[k].y);
                acc[k].x = fmaf(xv.w, w3.x, acc[k].x);
                acc[k].y = fmaf(xv.w, w3.y, acc[k].y);
            }
        }

        #pragma unroll
        for (int k = 0; k < GW; ++k) {
            const int idx = start + k;
            if (idx < row1) {
                ushort2 o;
                o.x = f2bf(acc[k].x);
                o.y = f2bf(acc[k].y);
                *(ushort2*)&y[(size_t)elist[idx] * 128 + 2 * t] = o;
            }
        }

        __syncthreads();   // xsd reads done before next-iteration restage
    }
}

// ---------------- final plain linear 128 -> 64, 8 nodes/block (bf16 out) -----
__global__ __launch_bounds__(64) void last_kernel(
    const float* __restrict__ h, const float* __restrict__ W,
    unsigned short* __restrict__ y)
{
    __shared__ float xs[NB][128];
    const int n0 = blockIdx.x * NB, t = threadIdx.x;
    #pragma unroll
    for (int j = 0; j < NB; ++j) {
        xs[j][t] = h[(size_t)(n0 + j) * 128 + t];
        xs[j][t + 64] = h[(size_t)(n0 + j) * 128 + t + 64];
    }
    __syncthreads();
    float a0 = 0.f, a1 = 0.f, a2 = 0.f, a3 = 0.f;
    float a4 = 0.f, a5 = 0.f, a6 = 0.f, a7 = 0.f;
    #pragma unroll 4
    for (int d = 0; d < 128; ++d) {
        const float w = W[d * 64 + t];
        a0 = fmaf(xs[0][d], w, a0);
        a1 = fmaf(xs[1][d], w, a1);
        a2 = fmaf(xs[2][d], w, a2);
        a3 = fmaf(xs[3][d], w, a3);
        a4 = fmaf(xs[4][d], w, a4);
        a5 = fmaf(xs[5][d], w, a5);
        a6 = fmaf(xs[6][d], w, a6);
        a7 = fmaf(xs[7][d], w, a7);
    }
    y[(size_t)(n0 + 0) * 64 + t] = f2bf(a0);
    y[(size_t)(n0 + 1) * 64 + t] = f2bf(a1);
    y[(size_t)(n0 + 2) * 64 + t] = f2bf(a2);
    y[(size_t)(n0 + 3) * 64 + t] = f2bf(a3);
    y[(size_t)(n0 + 4) * 64 + t] = f2bf(a4);
    y[(size_t)(n0 + 5) * 64 + t] = f2bf(a5);
    y[(size_t)(n0 + 6) * 64 + t] = f2bf(a6);
    y[(size_t)(n0 + 7) * 64 + t] = f2bf(a7);
}

// ============== CSR build: bucketed counting sort, NO global atomics =========
__global__ __launch_bounds__(256) void bhist_kernel(
    const int* __restrict__ edst, int* __restrict__ hist_g)
{
    __shared__ int lcnt[NBUK];
    const int t = threadIdx.x;
    const int b = blockIdx.x;
    for (int i = t; i < NBUK; i += 256) lcnt[i] = 0;
    __syncthreads();
    const int e0 = b * EPB;
    #pragma unroll 5
    for (int k = 0; k < EPB / 256; ++k)
        atomicAdd(&lcnt[edst[e0 + k * 256 + t] >> 6], 1);
    __syncthreads();
    for (int i = t; i < NBUK; i += 256) hist_g[i * NFB + b] = lcnt[i];
}

__global__ __launch_bounds__(256) void hpre_kernel(
    const int* __restrict__ hist_g, int* __restrict__ tsum)
{
    __shared__ int ws[4];
    const int t = threadIdx.x;
    const int idx = blockIdx.x * 256 + t;
    int v = (idx < HM) ? hist_g[idx] : 0;
    #pragma unroll
    for (int m = 32; m >= 1; m >>= 1) v += __shfl_xor(v, m, 64);
    if ((t & 63) == 0) ws[t >> 6] = v;
    __syncthreads();
    if (t == 0) tsum[blockIdx.x] = ws[0] + ws[1] + ws[2] + ws[3];
}

__global__ __launch_bounds__(1024) void hscan_kernel(
    const int* __restrict__ tsum, int* __restrict__ tbase, int* __restrict__ rowptr_last)
{
    __shared__ int buf[1024];
    const int t = threadIdx.x;
    const int v = (t < NSB2) ? tsum[t] : 0;
    buf[t] = v;
    __syncthreads();
    for (int off = 1; off < 1024; off <<= 1) {
        const int add = (t >= off) ? buf[t - off] : 0;
        __syncthreads();
        buf[t] += add;
        __syncthreads();
    }
    if (t < NSB2) tbase[t] = buf[t] - v;
    if (t == 0) rowptr_last[0] = N_EDGES;
}

__global__ __launch_bounds__(256) void hwb_kernel(
    const int* __restrict__ hist_g, const int* __restrict__ tbase,
    int* __restrict__ base_g)
{
    __shared__ int buf[256];
    const int t = threadIdx.x;
    const int idx = blockIdx.x * 256 + t;
    const int v = (idx < HM) ? hist_g[idx] : 0;
    buf[t] = v;
    __syncthreads();
    for (int off = 1; off < 256; off <<= 1) {
        const int add = (t >= off) ? buf[t - off] : 0;
        __syncthreads();
        buf[t] += add;
        __syncthreads();
    }
    if (idx < HM) base_g[idx] = buf[t] - v + tbase[blockIdx.x];
}

__global__ __launch_bounds__(256) void bscatter_kernel(
    const int* __restrict__ esrc, const int* __restrict__ edst,
    const int* __restrict__ base_g, unsigned int* __restrict__ packed)
{
    __shared__ int rcur[NBUK];
    const int t = threadIdx.x;
    const int b = blockIdx.x;
    for (int i = t; i < NBUK; i += 256) rcur[i] = base_g[i * NFB + b];
    __syncthreads();
    const int e0 = b * EPB;
    #pragma unroll 5
    for (int k = 0; k < EPB / 256; ++k) {
        const int i = e0 + k * 256 + t;
        const int src = esrc[i];
        const int dst = edst[i];
        const int p = atomicAdd(&rcur[dst >> 6], 1);
        packed[p] = ((unsigned int)dst << 16) | (unsigned int)src;
    }
}

__global__ __launch_bounds__(256) void bfine_kernel(
    const unsigned int* __restrict__ packed, const int* __restrict__ base_g,
    int* __restrict__ rowptr, unsigned short* __restrict__ csr_src)
{
    __shared__ int cnt64[64], cur64[64], sexcl[64];
    const int t = threadIdx.x;
    const int j = blockIdx.x;
    const int s0 = base_g[j * NFB];
    const int s1 = (j + 1 < NBUK) ? base_g[(j + 1) * NFB] : N_EDGES;
    if (t < 64) cnt64[t] = 0;
    __syncthreads();
    for (int i = s0 + t; i < s1; i += 256)
        atomicAdd(&cnt64[(packed[i] >> 16) & 63], 1);
    __syncthreads();
    if (t == 0) {
        int run = 0;
        #pragma unroll
        for (int l = 0; l < 64; ++l) { sexcl[l] = run; run += cnt64[l]; }
    }
    __syncthreads();
    if (t < 64) {
        cur64[t] = 0;
        const int n = (j << 6) + t;
        if (n < N_NODES) rowptr[n] = s0 + sexcl[t];
    }
    __syncthreads();
    for (int i = s0 + t; i < s1; i += 256) {
        const unsigned int pk = packed[i];
        const int dl = (pk >> 16) & 63;
        const int p = atomicAdd(&cur64[dl], 1);
        csr_src[s0 + sexcl[dl] + p] = (unsigned short)(pk & 0xffff);
    }
}

// ---------------- gather aggregation: out[n] = bias + sum_{e in row n} h[src] -
// h rows are BF16. 16 independent accumulator chains (R20 measured best:
// 65.2 us, occupancy 76%; the 32-chain tier of R21 regressed to 68.3).
template <int D, bool RELU>
__global__ __launch_bounds__(D) void gather_kernel(
    const unsigned short* __restrict__ h, const int* __restrict__ rowptr,
    const unsigned short* __restrict__ csr_src, const float* __restrict__ bias,
    float* __restrict__ out)
{
    const int n = blockIdx.x, t = threadIdx.x;
    const int s0 = rowptr[n], s1 = rowptr[n + 1];
    float a0 = bias[t], a1 = 0.f, a2 = 0.f, a3 = 0.f;
    float a4 = 0.f, a5 = 0.f, a6 = 0.f, a7 = 0.f;
    float a8 = 0.f, a9 = 0.f, aA = 0.f, aB = 0.f;
    float aC = 0.f, aD = 0.f, aE = 0.f, aF = 0.f;
    int e = s0;
    for (; e + 15 < s1; e += 16) {
        const int i0 = csr_src[e + 0];
        const int i1 = csr_src[e + 1];
        const int i2 = csr_src[e + 2];
        const int i3 = csr_src[e + 3];
        const int i4 = csr_src[e + 4];
        const int i5 = csr_src[e + 5];
        const int i6 = csr_src[e + 6];
        const int i7 = csr_src[e + 7];
        const int i8 = csr_src[e + 8];
        const int i9 = csr_src[e + 9];
        const int iA = csr_src[e + 10];
        const int iB = csr_src[e + 11];
        const int iC = csr_src[e + 12];
        const int iD = csr_src[e + 13];
        const int iE = csr_src[e + 14];
        const int iF = csr_src[e + 15];
        a0 += bf2f(h[(size_t)i0 * D + t]);
        a1 += bf2f(h[(size_t)i1 * D + t]);
        a2 += bf2f(h[(size_t)i2 * D + t]);
        a3 += bf2f(h[(size_t)i3 * D + t]);
        a4 += bf2f(h[(size_t)i4 * D + t]);
        a5 += bf2f(h[(size_t)i5 * D + t]);
        a6 += bf2f(h[(size_t)i6 * D + t]);
        a7 += bf2f(h[(size_t)i7 * D + t]);
        a8 += bf2f(h[(size_t)i8 * D + t]);
        a9 += bf2f(h[(size_t)i9 * D + t]);
        aA += bf2f(h[(size_t)iA * D + t]);
        aB += bf2f(h[(size_t)iB * D + t]);
        aC += bf2f(h[(size_t)iC * D + t]);
        aD += bf2f(h[(size_t)iD * D + t]);
        aE += bf2f(h[(size_t)iE * D + t]);
        aF += bf2f(h[(size_t)iF * D + t]);
    }
    for (; e + 7 < s1; e += 8) {
        const int i0 = csr_src[e + 0];
        const int i1 = csr_src[e + 1];
        const int i2 = csr_src[e + 2];
        const int i3 = csr_src[e + 3];
        const int i4 = csr_src[e + 4];
        const int i5 = csr_src[e + 5];
        const int i6 = csr_src[e + 6];
        const int i7 = csr_src[e + 7];
        a0 += bf2f(h[(size_t)i0 * D + t]);
        a1 += bf2f(h[(size_t)i1 * D + t]);
        a2 += bf2f(h[(size_t)i2 * D + t]);
        a3 += bf2f(h[(size_t)i3 * D + t]);
        a4 += bf2f(h[(size_t)i4 * D + t]);
        a5 += bf2f(h[(size_t)i5 * D + t]);
        a6 += bf2f(h[(size_t)i6 * D + t]);
        a7 += bf2f(h[(size_t)i7 * D + t]);
    }
    for (; e + 3 < s1; e += 4) {
        const int i0 = csr_src[e + 0];
        const int i1 = csr_src[e + 1];
        const int i2 = csr_src[e + 2];
        const int i3 = csr_src[e + 3];
        a0 += bf2f(h[(size_t)i0 * D + t]);
        a1 += bf2f(h[(size_t)i1 * D + t]);
        a2 += bf2f(h[(size_t)i2 * D + t]);
        a3 += bf2f(h[(size_t)i3 * D + t]);
    }
    for (; e < s1; ++e) a0 += bf2f(h[(size_t)csr_src[e] * D + t]);
    float acc = (((a0 + a1) + (a2 + a3)) + ((a4 + a5) + (a6 + a7)))
              + (((a8 + a9) + (aA + aB)) + ((aC + aD) + (aE + aF)));
    if (RELU) acc = fmaxf(acc, 0.f);
    out[(size_t)n * D + t] = acc;
}

// ---------------- finalize: reduce 2*NGBLK gate partials + write tail --------
__global__ __launch_bounds__(1024) void finalize_kernel(
    const float* __restrict__ gpart, float* __restrict__ out_tail)
{
    __shared__ float wsum[16];
    const int t = threadIdx.x;
    float s = 0.f;
    for (int i = t; i < 2 * NGBLK; i += 1024) s += gpart[i];
    #pragma unroll
    for (int m = 32; m >= 1; m >>= 1) s += __shfl_xor(s, m, 64);
    if ((t & 63) == 0) wsum[t >> 6] = s;
    __syncthreads();
    if (t == 0) {
        float tot = 0.f;
        #pragma unroll
        for (int w = 0; w < 16; ++w) tot += wsum[w];
        out_tail[0] = tot * (0.5f / (float)N_NODES);
        out_tail[1] = 1.0f;
    }
}

extern "C" void kernel_launch(void* const* d_in, const int* in_sizes, int n_in,
                              void* d_out, int out_size, void* d_ws, size_t ws_size,
                              hipStream_t stream)
{
    const float* x     = (const float*)d_in[0];
    const int*   edge  = (const int*)d_in[1];
    const float* Wg1   = (const float*)d_in[2];
    const float* bg1   = (const float*)d_in[3];
    const float* We1   = (const float*)d_in[4];
    const float* be1   = (const float*)d_in[5];
    const float* b1    = (const float*)d_in[6];
    const float* Wg2   = (const float*)d_in[7];
    const float* bg2   = (const float*)d_in[8];
    const float* We2   = (const float*)d_in[9];
    const float* be2   = (const float*)d_in[10];
    const float* b2    = (const float*)d_in[11];
    const float* Wlast = (const float*)d_in[12];
    const float* blast = (const float*)d_in[13];
    float* out = (float*)d_out;

    const int* esrc = edge;
    const int* edst = edge + N_EDGES;

    char* ws = (char*)d_ws;
    size_t off = 0;
    float* gpart = (float*)(ws + off); off += (size_t)2 * NGBLK * 4 + 252; off &= ~(size_t)255;
    float* A = (float*)(ws + off); off += (size_t)N_NODES * 128 * 4;
    float* B = (float*)(ws + off); off += (size_t)N_NODES * 128 * 4;
    int* rowptr = (int*)(ws + off); off += (size_t)(N_NODES + 1) * 4 + 252; off &= ~(size_t)255;
    int* eidx = (int*)(ws + off); off += (size_t)N_NODES * 4 + 252; off &= ~(size_t)255;
    unsigned short* csr_src = (unsigned short*)(ws + off); off += (size_t)N_EDGES * 2 + 252; off &= ~(size_t)255;
    int* elist = (int*)(ws + off); off += (size_t)N_NODES * 4 + 252; off &= ~(size_t)255;
    int* meta = (int*)(ws + off); off += 512;
    int* ecnt = meta;          // 16
    int* eoff = meta + 16;     // 17
    int* ecur = meta + 33;     // 16
    int* coff = meta + 49;     // 17 chunk offsets

    // bf16 intermediate h (per-expert / last outputs), lives in A's slab
    unsigned short* Abf = (unsigned short*)A;     // 12.8 MB (128-dim) / 6.4 MB (64-dim)

    // CSR temporaries alias A and B (both dead until layer 1 compute):
    unsigned int* packed = (unsigned int*)A;      // 6.4 MB <= 25.6 MB
    int* hist_g = (int*)B;                        // HM ints
    int* base_g = hist_g + HM;                    // HM ints
    int* tsum   = base_g + HM;                    // NSB2 ints
    int* tbase  = tsum + NSB2;                    // NSB2 ints (total ~1.6 MB)

    // ---- CSR build (no global atomics) ----
    bhist_kernel<<<NFB, 256, 0, stream>>>(edst, hist_g);
    hpre_kernel<<<NSB2, 256, 0, stream>>>(hist_g, tsum);
    hscan_kernel<<<1, 1024, 0, stream>>>(tsum, tbase, rowptr + N_NODES);
    hwb_kernel<<<NSB2, 256, 0, stream>>>(hist_g, tbase, base_g);
    bscatter_kernel<<<NFB, 256, 0, stream>>>(esrc, edst, base_g, packed);
    bfine_kernel<<<NBUK, 256, 0, stream>>>(packed, base_g, rowptr, csr_src);

    const int nbk = (N_NODES + 255) / 256;

    // ---- layer 1 ----
    gate_kernel<<<NGBLK, 256, 0, stream>>>(x, Wg1, bg1, eidx, gpart);
    hipMemsetAsync(ecnt, 0, 64, stream);
    hist16_kernel<<<nbk, 256, 0, stream>>>(eidx, ecnt);
    scan16_kernel<<<1, 64, 0, stream>>>(ecnt, eoff, ecur, coff);
    scatter16_kernel<<<nbk, 256, 0, stream>>>(eidx, ecur, elist);
    expert_gemm_kernel<<<NPB, 64, 0, stream>>>(x, We1, be1, eoff, coff, elist, Abf);
    gather_kernel<128, true><<<N_NODES, 128, 0, stream>>>(Abf, rowptr, csr_src, b1, B);

    // ---- layer 2 ----
    gate_kernel<<<NGBLK, 256, 0, stream>>>(B, Wg2, bg2, eidx, gpart + NGBLK);
    hipMemsetAsync(ecnt, 0, 64, stream);
    hist16_kernel<<<nbk, 256, 0, stream>>>(eidx, ecnt);
    scan16_kernel<<<1, 64, 0, stream>>>(ecnt, eoff, ecur, coff);
    scatter16_kernel<<<nbk, 256, 0, stream>>>(eidx, ecur, elist);
    expert_gemm_kernel<<<NPB, 64, 0, stream>>>(B, We2, be2, eoff, coff, elist, Abf);
    gather_kernel<128, true><<<N_NODES, 128, 0, stream>>>(Abf, rowptr, csr_src, b2, B);

    // ---- layer 3 (plain GCNConv) ----
    last_kernel<<<N_NODES / NB, 64, 0, stream>>>(B, Wlast, Abf);
    gather_kernel<64, false><<<N_NODES, 64, 0, stream>>>(Abf, rowptr, csr_src, blast, out);

    finalize_kernel<<<1, 1024, 0, stream>>>(gpart, out + (size_t)N_NODES * 64);
}